// Round 6
// baseline (508.229 us; speedup 1.0000x reference)
//
#include <hip/hip_runtime.h>

#define N_NODES 50000
#define E_EDGES 1600000
#define NEG 0.2f
#define EDGE_BLOCKS 6250                    // one edge per thread: 6250*256 == E_EDGES
#define SCAN_BLOCKS ((N_NODES + 255)/256)   // 196

__device__ __forceinline__ float lrelu(float x){ return x > 0.f ? x : NEG*x; }
__device__ __forceinline__ float bcastlane(float v, int k){
    return __int_as_float(__builtin_amdgcn_readlane(__float_as_int(v), k));
}
__device__ __forceinline__ unsigned bf16rn(float x){
    unsigned u = __float_as_uint(x);
    return (u + 0x7FFFu + ((u >> 16) & 1u)) >> 16;
}
__device__ __forceinline__ float bf2f(unsigned short u){
    return __uint_as_float(((unsigned)u) << 16);
}
__device__ __forceinline__ float bfsel(unsigned pk, int hi){
    return __uint_as_float(hi ? (pk & 0xFFFF0000u) : (pk << 16));
}

// small[] layout (floats): [16..32) mean, [32..96) WeAtt1[k*4+h], [96..160) WeAtt2,
// [160..164) aeloop1, [164..168) aeloop2

__global__ void k_prep1(const float* __restrict__ We1, const float* __restrict__ atte1,
                        const float* __restrict__ We2, const float* __restrict__ atte2,
                        float* __restrict__ small){
    int t = threadIdx.x;            // 64 threads: t = k*4+h
    int k = t >> 2, hh = t & 3;
    float w1 = 0.f, w2 = 0.f;
    for (int c = 0; c < 16; ++c){
        w1 = fmaf(We1[k*64 + hh*16 + c], atte1[hh*16 + c], w1);
        w2 = fmaf(We2[k*64 + hh*16 + c], atte2[hh*16 + c], w2);
    }
    small[32 + t] = w1;
    small[96 + t] = w2;
}

// histogram + per-edge rank within its dst (atomicAdd return value)
__global__ __launch_bounds__(256) void k_hist(const int4* __restrict__ dst4, int* __restrict__ deg,
                                              int4* __restrict__ rank4){
    int i = blockIdx.x*256 + threadIdx.x;
    if (i < E_EDGES/4){
        int4 v = dst4[i];
        int4 r;
        r.x = atomicAdd(&deg[v.x], 1);
        r.y = atomicAdd(&deg[v.y], 1);
        r.z = atomicAdd(&deg[v.z], 1);
        r.w = atomicAdd(&deg[v.w], 1);
        rank4[i] = r;
    }
}

// ---- hierarchical scan ----
__global__ __launch_bounds__(256) void k_scan_a(const int* __restrict__ deg, int* __restrict__ bsum){
    int i = blockIdx.x*256 + threadIdx.x;
    int v = (i < N_NODES) ? deg[i] : 0;
    v += __shfl_xor(v,1); v += __shfl_xor(v,2); v += __shfl_xor(v,4);
    v += __shfl_xor(v,8); v += __shfl_xor(v,16); v += __shfl_xor(v,32);
    __shared__ int ws[4];
    if ((threadIdx.x & 63) == 0) ws[threadIdx.x >> 6] = v;
    __syncthreads();
    if (threadIdx.x == 0) bsum[blockIdx.x] = ws[0] + ws[1] + ws[2] + ws[3];
}

__global__ __launch_bounds__(256) void k_scan_b(const int* __restrict__ bsum, int* __restrict__ boff){
    __shared__ int sm[256];
    int t = threadIdx.x;
    int v = (t < SCAN_BLOCKS) ? bsum[t] : 0;
    sm[t] = v;
    __syncthreads();
    for (int off = 1; off < 256; off <<= 1){
        int u = (t >= off) ? sm[t-off] : 0;
        __syncthreads();
        sm[t] += u;
        __syncthreads();
    }
    boff[t] = (t > 0) ? sm[t-1] : 0;
    if (t == 0) boff[SCAN_BLOCKS] = sm[255];
}

__global__ __launch_bounds__(256) void k_scan_c(const int* __restrict__ deg, const int* __restrict__ boff,
                                                int* __restrict__ base){
    int i = blockIdx.x*256 + threadIdx.x;
    int lane = threadIdx.x & 63, wid = threadIdx.x >> 6;
    int v = (i < N_NODES) ? deg[i] : 0;
    int inc = v;
    for (int off = 1; off < 64; off <<= 1){
        int u = __shfl_up(inc, off);
        if (lane >= off) inc += u;
    }
    __shared__ int wsum[4];
    if (lane == 63) wsum[wid] = inc;
    __syncthreads();
    int wpre = 0;
#pragma unroll
    for (int w = 0; w < 4; ++w) wpre += (w < wid) ? wsum[w] : 0;
    int ex = boff[blockIdx.x] + wpre + inc - v;
    if (i < N_NODES) base[i] = ex;
    if (i == N_NODES - 1) base[N_NODES] = ex + v;
}

// h = in @ W  (N x FIN @ FIN x 64) -> bf16 gather table; a_s/a_d per (node, head).
template<int FIN>
__global__ __launch_bounds__(256) void k_node(const float* __restrict__ in, const float* __restrict__ W,
                                              const float* __restrict__ att_s, const float* __restrict__ att_d,
                                              unsigned short* __restrict__ hb, float* __restrict__ a_s,
                                              float* __restrict__ a_d){
    __shared__ float Wl[FIN*64];
    for (int i = threadIdx.x; i < FIN*64; i += 256) Wl[i] = W[i];
    __syncthreads();
    int lane = threadIdx.x & 63;
    int node = blockIdx.x*4 + (threadIdx.x >> 6);
    const float* row = in + (size_t)node*FIN;
    float x0 = row[lane];
    float x1 = 0.f;
    if constexpr (FIN == 128) x1 = row[64 + lane];
    float acc = 0.f;
#pragma unroll
    for (int k = 0; k < 64; ++k)
        acc = fmaf(bcastlane(x0, k), Wl[k*64 + lane], acc);
    if constexpr (FIN == 128){
#pragma unroll
        for (int k = 0; k < 64; ++k)
            acc = fmaf(bcastlane(x1, k), Wl[(64+k)*64 + lane], acc);
    }
    hb[(size_t)node*64 + lane] = (unsigned short)bf16rn(acc);
    float ps = acc * att_s[lane];
    float pd = acc * att_d[lane];
    ps += __shfl_xor(ps,1); ps += __shfl_xor(ps,2); ps += __shfl_xor(ps,4); ps += __shfl_xor(ps,8);
    pd += __shfl_xor(pd,1); pd += __shfl_xor(pd,2); pd += __shfl_xor(pd,4); pd += __shfl_xor(pd,8);
    if ((lane & 15) == 0){
        a_s[node*4 + (lane>>4)] = ps;
        a_d[node*4 + (lane>>4)] = pd;
    }
}

// Fused edge pass, one edge per thread, NO atomic: p = base[d] + rank[e].
// Writes ONE 32B scattered record: r0={si, w1pk01, w1pk23, d}, r1={ae2pk01, ae2pk23, 0, 0}.
// Also reduces column sums of ea for the mean self-loop attr.
__global__ __launch_bounds__(256) void k_edges(const int* __restrict__ src, const int* __restrict__ dst,
                                               const int* __restrict__ rank,
                                               const float* __restrict__ ea, const float* __restrict__ small,
                                               const float* __restrict__ a_s, const float* __restrict__ a_d,
                                               const int* __restrict__ base, uint4* __restrict__ rec,
                                               float* __restrict__ partials){
    __shared__ float w1[64], w2[64];
    __shared__ float red[64];
    if (threadIdx.x < 64){ w1[threadIdx.x] = small[32+threadIdx.x]; w2[threadIdx.x] = small[96+threadIdx.x]; }
    __syncthreads();
    int e = blockIdx.x*256 + threadIdx.x;   // grid covers E exactly
    int s = src[e], d = dst[e], rk = rank[e];
    int p = base[d] + rk;
    const float4 as4 = *(const float4*)(a_s + (size_t)s*4);
    const float4 ad4 = *(const float4*)(a_d + (size_t)d*4);
    const float4* eap = (const float4*)(ea + (size_t)e*16);
    float cs[16];
    float ae1[4] = {0,0,0,0}, ae2[4] = {0,0,0,0};
#pragma unroll
    for (int q = 0; q < 4; ++q){
        float4 v4 = eap[q];
        float vv[4] = {v4.x, v4.y, v4.z, v4.w};
#pragma unroll
        for (int r = 0; r < 4; ++r){
            int k = q*4 + r;
            float xv = vv[r];
            cs[k] = xv;
#pragma unroll
            for (int hh = 0; hh < 4; ++hh){
                ae1[hh] = fmaf(xv, w1[k*4+hh], ae1[hh]);
                ae2[hh] = fmaf(xv, w2[k*4+hh], ae2[hh]);
            }
        }
    }
    float wv0 = __expf(lrelu(as4.x + ad4.x + ae1[0]));
    float wv1 = __expf(lrelu(as4.y + ad4.y + ae1[1]));
    float wv2 = __expf(lrelu(as4.z + ad4.z + ae1[2]));
    float wv3 = __expf(lrelu(as4.w + ad4.w + ae1[3]));
    uint4 r0, r1;
    r0.x = (unsigned)s;
    r0.y = bf16rn(wv0) | (bf16rn(wv1) << 16);
    r0.z = bf16rn(wv2) | (bf16rn(wv3) << 16);
    r0.w = (unsigned)d;
    r1.x = bf16rn(ae2[0]) | (bf16rn(ae2[1]) << 16);
    r1.y = bf16rn(ae2[2]) | (bf16rn(ae2[3]) << 16);
    r1.z = 0u; r1.w = 0u;
    rec[(size_t)p*2]     = r0;
    rec[(size_t)p*2 + 1] = r1;
    // block-reduce column sums -> partials[block][16]
#pragma unroll
    for (int k = 0; k < 16; ++k){
        float v = cs[k];
        v += __shfl_xor(v,1); v += __shfl_xor(v,2); v += __shfl_xor(v,4);
        v += __shfl_xor(v,8); v += __shfl_xor(v,16); v += __shfl_xor(v,32);
        if ((threadIdx.x & 63) == 0) red[k*4 + (threadIdx.x>>6)] = v;
    }
    __syncthreads();
    if (threadIdx.x < 16){
        float v = red[threadIdx.x*4] + red[threadIdx.x*4+1] + red[threadIdx.x*4+2] + red[threadIdx.x*4+3];
        partials[blockIdx.x*16 + threadIdx.x] = v;
    }
}

__global__ __launch_bounds__(256) void k_prep2(float* __restrict__ small, const float* __restrict__ partials){
    __shared__ float sm[256];
    __shared__ float mean_s[16];
    int t = threadIdx.x;
    float v = 0.f;
    for (int r = (t>>4); r < EDGE_BLOCKS; r += 16) v += partials[r*16 + (t&15)];
    sm[t] = v;
    __syncthreads();
    if (t < 16){
        float s = 0.f;
#pragma unroll
        for (int i = 0; i < 16; ++i) s += sm[t + 16*i];
        float m = s * (1.0f/(float)E_EDGES);
        mean_s[t] = m; small[16+t] = m;
    }
    __syncthreads();
    if (t < 4){
        float a1 = 0.f, a2 = 0.f;
#pragma unroll
        for (int k = 0; k < 16; ++k){
            a1 = fmaf(mean_s[k], small[32 + k*4 + t], a1);
            a2 = fmaf(mean_s[k], small[96 + k*4 + t], a2);
        }
        small[160+t] = a1; small[164+t] = a2;
    }
}

// Layer-2 weight pass: thread-per-CSR-slot, linear streams. Reads rec, gathers
// a_s2/a_d2 (L2-resident), writes compact c2 = {si, w2pk01, w2pk23, 0}.
__global__ __launch_bounds__(256) void k_w2(const uint4* __restrict__ rec,
                                            const float* __restrict__ a_s, const float* __restrict__ a_d,
                                            uint4* __restrict__ c2){
    int p = blockIdx.x*256 + threadIdx.x;
    if (p >= E_EDGES) return;
    uint4 r0 = rec[(size_t)p*2];
    uint2 r1 = *(const uint2*)&rec[(size_t)p*2 + 1];
    int si = (int)r0.x, d = (int)r0.w;
    const float4 as4 = *(const float4*)(a_s + (size_t)si*4);
    const float4 ad4 = *(const float4*)(a_d + (size_t)d*4);
    float w0 = __expf(lrelu(as4.x + ad4.x + bfsel(r1.x, 0)));
    float w1 = __expf(lrelu(as4.y + ad4.y + bfsel(r1.x, 1)));
    float w2 = __expf(lrelu(as4.z + ad4.z + bfsel(r1.y, 0)));
    float w3 = __expf(lrelu(as4.w + ad4.w + bfsel(r1.y, 1)));
    uint4 o;
    o.x = r0.x;
    o.y = bf16rn(w0) | (bf16rn(w1) << 16);
    o.z = bf16rn(w2) | (bf16rn(w3) << 16);
    o.w = 0u;
    c2[p] = o;
}

// One wave per node, lane = head*16+chan. Per edge: ONE uniform 16B record
// {si, wpk01, wpk23, _} (STRIDE uint4s apart) + one hb gather + 2 fma.
// 4-way unrolled independent accumulator chains for MLP.
template<int STRIDE>
__global__ __launch_bounds__(256) void k_agg(const uint4* __restrict__ recs, const int* __restrict__ base,
                                             const unsigned short* __restrict__ hb,
                                             const float* __restrict__ a_s, const float* __restrict__ a_d,
                                             const float* __restrict__ aeloop, const float* __restrict__ bias,
                                             float* __restrict__ out){
    int lane = threadIdx.x & 63;
    int n = blockIdx.x*4 + (threadIdx.x >> 6);
    int hh = lane >> 4;
    int hi = hh & 1;
    float wL = __expf(lrelu(a_s[n*4+hh] + a_d[n*4+hh] + aeloop[hh]));
    float s0 = wL, s1 = 0.f, s2 = 0.f, s3 = 0.f;
    float acc0 = wL * bf2f(hb[(size_t)n*64 + lane]);
    float acc1 = 0.f, acc2 = 0.f, acc3 = 0.f;
    int b0 = base[n], b1 = base[n+1];
    int p = b0;
    for (; p + 4 <= b1; p += 4){
        uint4 rA = recs[(size_t)p*STRIDE];
        uint4 rB = recs[(size_t)(p+1)*STRIDE];
        uint4 rC = recs[(size_t)(p+2)*STRIDE];
        uint4 rD = recs[(size_t)(p+3)*STRIDE];
        float hvA = bf2f(hb[(size_t)rA.x*64 + lane]);
        float hvB = bf2f(hb[(size_t)rB.x*64 + lane]);
        float hvC = bf2f(hb[(size_t)rC.x*64 + lane]);
        float hvD = bf2f(hb[(size_t)rD.x*64 + lane]);
        float wA = bfsel((hh < 2) ? rA.y : rA.z, hi);
        float wB = bfsel((hh < 2) ? rB.y : rB.z, hi);
        float wC = bfsel((hh < 2) ? rC.y : rC.z, hi);
        float wD = bfsel((hh < 2) ? rD.y : rD.z, hi);
        s0 += wA; acc0 = fmaf(wA, hvA, acc0);
        s1 += wB; acc1 = fmaf(wB, hvB, acc1);
        s2 += wC; acc2 = fmaf(wC, hvC, acc2);
        s3 += wD; acc3 = fmaf(wD, hvD, acc3);
    }
    for (; p < b1; ++p){
        uint4 r = recs[(size_t)p*STRIDE];
        float hv = bf2f(hb[(size_t)r.x*64 + lane]);
        float w = bfsel((hh < 2) ? r.y : r.z, hi);
        s1 += w; acc1 = fmaf(w, hv, acc1);
    }
    float s = (s0 + s1) + (s2 + s3);
    float val = ((acc0 + acc1) + (acc2 + acc3)) / (s + 1e-16f) + bias[lane];
    out[(size_t)n*64 + lane] = fmaxf(val, 0.f);
}

__global__ __launch_bounds__(256) void k_head(const float* __restrict__ h2,
                                              const float* __restrict__ lw1, const float* __restrict__ lb1,
                                              const float* __restrict__ lw2, const float* __restrict__ lb2,
                                              float* __restrict__ out){
    int n = blockIdx.x*256 + threadIdx.x;
    if (n >= N_NODES) return;
    float y16[16];
#pragma unroll
    for (int j = 0; j < 16; ++j) y16[j] = lb1[j];
    const float4* hp = (const float4*)(h2 + (size_t)n*64);
#pragma unroll
    for (int k4 = 0; k4 < 16; ++k4){
        float4 hv = hp[k4];
        float hvv[4] = {hv.x, hv.y, hv.z, hv.w};
#pragma unroll
        for (int r = 0; r < 4; ++r){
            float x = hvv[r];
            int k = k4*4 + r;
#pragma unroll
            for (int j = 0; j < 16; ++j) y16[j] = fmaf(x, lw1[k*16+j], y16[j]);
        }
    }
    float y[40];
#pragma unroll
    for (int o = 0; o < 40; ++o) y[o] = lb2[o];
#pragma unroll
    for (int j = 0; j < 16; ++j){
        float x = y16[j];
#pragma unroll
        for (int o = 0; o < 40; ++o) y[o] = fmaf(x, lw2[j*40+o], y[o]);
    }
    float mx = y[0];
#pragma unroll
    for (int o = 1; o < 40; ++o) mx = fmaxf(mx, y[o]);
    float sum = 0.f;
#pragma unroll
    for (int o = 0; o < 40; ++o) sum += __expf(y[o] - mx);
    float ls = __logf(sum) + mx;
    float* op = out + (size_t)n*40;
#pragma unroll
    for (int o = 0; o < 40; ++o) op[o] = y[o] - ls;
}

extern "C" void kernel_launch(void* const* d_in, const int* in_sizes, int n_in,
                              void* d_out, int out_size, void* d_ws, size_t ws_size,
                              hipStream_t stream){
    const float* x     = (const float*)d_in[0];
    const int*   ei    = (const int*)  d_in[1];
    const float* ea    = (const float*)d_in[2];
    const float* W1    = (const float*)d_in[3];
    const float* atts1 = (const float*)d_in[4];
    const float* attd1 = (const float*)d_in[5];
    const float* We1   = (const float*)d_in[6];
    const float* atte1 = (const float*)d_in[7];
    const float* b1    = (const float*)d_in[8];
    const float* W2    = (const float*)d_in[9];
    const float* atts2 = (const float*)d_in[10];
    const float* attd2 = (const float*)d_in[11];
    const float* We2   = (const float*)d_in[12];
    const float* atte2 = (const float*)d_in[13];
    const float* b2    = (const float*)d_in[14];
    const float* lw1   = (const float*)d_in[15];
    const float* lb1   = (const float*)d_in[16];
    const float* lw2   = (const float*)d_in[17];
    const float* lb2   = (const float*)d_in[18];
    float* outp = (float*)d_out;

    const int* srcp = ei;
    const int* dstp = ei + E_EDGES;

    char* ws = (char*)d_ws;
    size_t off = 0;
    auto alloc = [&](size_t bytes) -> void* {
        void* p = ws + off;
        off = (off + bytes + 255) & ~(size_t)255;
        return p;
    };
    float*  smallf   = (float*) alloc(256*sizeof(float));
    float*  partials = (float*) alloc((size_t)EDGE_BLOCKS*16*sizeof(float));
    int*    deg      = (int*)   alloc((size_t)N_NODES*sizeof(int));
    int*    base     = (int*)   alloc((size_t)(N_NODES+1)*sizeof(int));
    int*    bsum     = (int*)   alloc((size_t)(SCAN_BLOCKS+1)*sizeof(int));
    int*    boff     = (int*)   alloc((size_t)(SCAN_BLOCKS+1)*sizeof(int));
    int*    rank     = (int*)   alloc((size_t)E_EDGES*sizeof(int));
    uint4*  rec      = (uint4*) alloc((size_t)E_EDGES*32);
    uint4*  c2       = (uint4*) alloc((size_t)E_EDGES*16);
    unsigned short* hb = (unsigned short*)alloc((size_t)N_NODES*64*sizeof(unsigned short));
    float*  obuf     = (float*) alloc((size_t)N_NODES*64*sizeof(float));
    float*  asb      = (float*) alloc((size_t)N_NODES*4*sizeof(float));
    float*  adb      = (float*) alloc((size_t)N_NODES*4*sizeof(float));

    const int NB = N_NODES/4;             // 12500
    const int HB = (N_NODES + 255)/256;   // 196
    const int EB = (E_EDGES + 255)/256;   // 6250

    hipMemsetAsync(deg, 0, (size_t)N_NODES*sizeof(int), stream);
    k_prep1<<<1, 64, 0, stream>>>(We1, atte1, We2, atte2, smallf);
    k_hist<<<(E_EDGES/4 + 255)/256, 256, 0, stream>>>((const int4*)dstp, deg, (int4*)rank);
    k_scan_a<<<SCAN_BLOCKS, 256, 0, stream>>>(deg, bsum);
    k_scan_b<<<1, 256, 0, stream>>>(bsum, boff);
    k_scan_c<<<SCAN_BLOCKS, 256, 0, stream>>>(deg, boff, base);

    // ---- layer 1 ----
    k_node<128><<<NB, 256, 0, stream>>>(x, W1, atts1, attd1, hb, asb, adb);
    k_edges<<<EDGE_BLOCKS, 256, 0, stream>>>(srcp, dstp, rank, ea, smallf, asb, adb,
                                             base, rec, partials);
    k_prep2<<<1, 256, 0, stream>>>(smallf, partials);
    k_agg<2><<<NB, 256, 0, stream>>>(rec, base, hb, asb, adb, smallf + 160, b1, obuf);

    // ---- layer 2 ----
    k_node<64><<<NB, 256, 0, stream>>>(obuf, W2, atts2, attd2, hb, asb, adb);
    k_w2<<<EB, 256, 0, stream>>>(rec, asb, adb, c2);
    k_agg<1><<<NB, 256, 0, stream>>>(c2, base, hb, asb, adb, smallf + 164, b2, obuf);

    // ---- head ----
    k_head<<<HB, 256, 0, stream>>>(obuf, lw1, lb1, lw2, lb2, outp);
}

// Round 7
// 463.291 us; speedup vs baseline: 1.0970x; 1.0970x over previous
//
#include <hip/hip_runtime.h>
#include <hip/hip_fp16.h>

#define N_NODES 50000
#define E_EDGES 1600000
#define NEG 0.2f
#define EDGE_BLOCKS 6250                    // one edge per thread: 6250*256 == E_EDGES
#define SCAN_BLOCKS ((N_NODES + 255)/256)   // 196

__device__ __forceinline__ float lrelu(float x){ return fmaxf(x, NEG*x); }
__device__ __forceinline__ float bcastlane(float v, int k){
    return __int_as_float(__builtin_amdgcn_readlane(__float_as_int(v), k));
}
__device__ __forceinline__ unsigned bf16rn(float x){
    unsigned u = __float_as_uint(x);
    return (u + 0x7FFFu + ((u >> 16) & 1u)) >> 16;
}
__device__ __forceinline__ float bf2f(unsigned short u){
    return __uint_as_float(((unsigned)u) << 16);
}
__device__ __forceinline__ unsigned h16(float x){
    return (unsigned)__half_as_ushort(__float2half(x));
}
__device__ __forceinline__ float f16dec(unsigned u){
    return __half2float(__ushort_as_half((unsigned short)(u & 0xFFFFu)));
}

// ---- fp8 e4m3 (OCP) encode/decode: hw builtins when available, manual fallback ----
#if __has_builtin(__builtin_amdgcn_cvt_f32_fp8) && __has_builtin(__builtin_amdgcn_cvt_pk_fp8_f32)
__device__ __forceinline__ unsigned enc8(float x){
    return (unsigned)__builtin_amdgcn_cvt_pk_fp8_f32(x, x, 0, false) & 0xFFu;
}
__device__ __forceinline__ float dec8(unsigned b){
    return __builtin_amdgcn_cvt_f32_fp8((int)b, 0);
}
#else
__device__ __forceinline__ unsigned enc8(float x){
    float ax = fabsf(x); unsigned s = (x < 0.f) ? 0x80u : 0u;
    if (ax < 0.015625f){
        int q = (int)rintf(ax * 512.f);          // subnormal quantum 2^-9; q==8 -> min normal
        return s | (unsigned)q;
    }
    if (ax >= 448.f) return s | 0x7Eu;           // max finite e4m3fn
    int ee; float mm = frexpf(ax, &ee);          // ax = mm*2^ee, mm in [0.5,1)
    int q = (int)rintf(mm * 16.f);               // [8,16]
    int E = ee + 6;                              // (ee-1)+7 bias
    if (q == 16){ q = 8; ++E; }
    if (E > 15){ return s | 0x7Eu; }
    return s | ((unsigned)E << 3) | (unsigned)(q - 8);
}
__device__ __forceinline__ float dec8(unsigned b){
    unsigned s = b >> 7, e = (b >> 3) & 15u, m = b & 7u;
    float mag = e ? __uint_as_float(((e + 120u) << 23) | (m << 20))
                  : (float)m * 0.001953125f;
    return s ? -mag : mag;
}
#endif

// small[] layout (floats): [16..32) mean, [32..96) WeAtt1[k*4+h], [96..160) WeAtt2,
// [160..164) aeloop1, [164..168) aeloop2

__global__ void k_prep1(const float* __restrict__ We1, const float* __restrict__ atte1,
                        const float* __restrict__ We2, const float* __restrict__ atte2,
                        float* __restrict__ small){
    int t = threadIdx.x;            // 64 threads: t = k*4+h
    int k = t >> 2, hh = t & 3;
    float w1 = 0.f, w2 = 0.f;
    for (int c = 0; c < 16; ++c){
        w1 = fmaf(We1[k*64 + hh*16 + c], atte1[hh*16 + c], w1);
        w2 = fmaf(We2[k*64 + hh*16 + c], atte2[hh*16 + c], w2);
    }
    small[32 + t] = w1;
    small[96 + t] = w2;
}

// histogram + per-edge rank within its dst (atomicAdd return value), rank as u16
__global__ __launch_bounds__(256) void k_hist(const int4* __restrict__ dst4, int* __restrict__ deg,
                                              ushort4* __restrict__ rank4){
    int i = blockIdx.x*256 + threadIdx.x;
    if (i < E_EDGES/4){
        int4 v = dst4[i];
        ushort4 r;
        r.x = (unsigned short)atomicAdd(&deg[v.x], 1);
        r.y = (unsigned short)atomicAdd(&deg[v.y], 1);
        r.z = (unsigned short)atomicAdd(&deg[v.z], 1);
        r.w = (unsigned short)atomicAdd(&deg[v.w], 1);
        rank4[i] = r;
    }
}

// ---- hierarchical scan ----
__global__ __launch_bounds__(256) void k_scan_a(const int* __restrict__ deg, int* __restrict__ bsum){
    int i = blockIdx.x*256 + threadIdx.x;
    int v = (i < N_NODES) ? deg[i] : 0;
    v += __shfl_xor(v,1); v += __shfl_xor(v,2); v += __shfl_xor(v,4);
    v += __shfl_xor(v,8); v += __shfl_xor(v,16); v += __shfl_xor(v,32);
    __shared__ int ws[4];
    if ((threadIdx.x & 63) == 0) ws[threadIdx.x >> 6] = v;
    __syncthreads();
    if (threadIdx.x == 0) bsum[blockIdx.x] = ws[0] + ws[1] + ws[2] + ws[3];
}

__global__ __launch_bounds__(256) void k_scan_b(const int* __restrict__ bsum, int* __restrict__ boff){
    __shared__ int sm[256];
    int t = threadIdx.x;
    int v = (t < SCAN_BLOCKS) ? bsum[t] : 0;
    sm[t] = v;
    __syncthreads();
    for (int off = 1; off < 256; off <<= 1){
        int u = (t >= off) ? sm[t-off] : 0;
        __syncthreads();
        sm[t] += u;
        __syncthreads();
    }
    boff[t] = (t > 0) ? sm[t-1] : 0;
    if (t == 0) boff[SCAN_BLOCKS] = sm[255];
}

__global__ __launch_bounds__(256) void k_scan_c(const int* __restrict__ deg, const int* __restrict__ boff,
                                                int* __restrict__ base){
    int i = blockIdx.x*256 + threadIdx.x;
    int lane = threadIdx.x & 63, wid = threadIdx.x >> 6;
    int v = (i < N_NODES) ? deg[i] : 0;
    int inc = v;
    for (int off = 1; off < 64; off <<= 1){
        int u = __shfl_up(inc, off);
        if (lane >= off) inc += u;
    }
    __shared__ int wsum[4];
    if (lane == 63) wsum[wid] = inc;
    __syncthreads();
    int wpre = 0;
#pragma unroll
    for (int w = 0; w < 4; ++w) wpre += (w < wid) ? wsum[w] : 0;
    int ex = boff[blockIdx.x] + wpre + inc - v;
    if (i < N_NODES) base[i] = ex;
    if (i == N_NODES - 1) base[N_NODES] = ex + v;
}

// h = in @ W -> fp8 gather table (3.2MB, fits per-XCD L2); a_s/a_d bf16 tables.
template<int FIN>
__global__ __launch_bounds__(256) void k_node(const float* __restrict__ in, const float* __restrict__ W,
                                              const float* __restrict__ att_s, const float* __restrict__ att_d,
                                              unsigned char* __restrict__ hb8,
                                              unsigned short* __restrict__ a_s,
                                              unsigned short* __restrict__ a_d){
    __shared__ float Wl[FIN*64];
    for (int i = threadIdx.x; i < FIN*64; i += 256) Wl[i] = W[i];
    __syncthreads();
    int lane = threadIdx.x & 63;
    int node = blockIdx.x*4 + (threadIdx.x >> 6);
    const float* row = in + (size_t)node*FIN;
    float x0 = row[lane];
    float x1 = 0.f;
    if constexpr (FIN == 128) x1 = row[64 + lane];
    float acc = 0.f;
#pragma unroll
    for (int k = 0; k < 64; ++k)
        acc = fmaf(bcastlane(x0, k), Wl[k*64 + lane], acc);
    if constexpr (FIN == 128){
#pragma unroll
        for (int k = 0; k < 64; ++k)
            acc = fmaf(bcastlane(x1, k), Wl[(64+k)*64 + lane], acc);
    }
    hb8[(size_t)node*64 + lane] = (unsigned char)enc8(acc);
    float ps = acc * att_s[lane];
    float pd = acc * att_d[lane];
    ps += __shfl_xor(ps,1); ps += __shfl_xor(ps,2); ps += __shfl_xor(ps,4); ps += __shfl_xor(ps,8);
    pd += __shfl_xor(pd,1); pd += __shfl_xor(pd,2); pd += __shfl_xor(pd,4); pd += __shfl_xor(pd,8);
    if ((lane & 15) == 0){
        a_s[node*4 + (lane>>4)] = (unsigned short)bf16rn(ps);
        a_d[node*4 + (lane>>4)] = (unsigned short)bf16rn(pd);
    }
}

// Edge pass: ae1 (f16x4) + ae2 (u8 fixed, (q-128)/256) -> ONE 16B scattered record
// {si, ae1pk01, ae1pk23, ae2q8x4}. No gathers except base[d]. Also ea column sums.
__global__ __launch_bounds__(256) void k_edges(const int* __restrict__ src, const int* __restrict__ dst,
                                               const unsigned short* __restrict__ rank,
                                               const float* __restrict__ ea, const float* __restrict__ small,
                                               const int* __restrict__ base, uint4* __restrict__ rec,
                                               float* __restrict__ partials){
    __shared__ float w1[64], w2[64];
    __shared__ float red[64];
    if (threadIdx.x < 64){ w1[threadIdx.x] = small[32+threadIdx.x]; w2[threadIdx.x] = small[96+threadIdx.x]; }
    __syncthreads();
    int e = blockIdx.x*256 + threadIdx.x;   // grid covers E exactly
    int s = src[e], d = dst[e];
    int rk = (int)rank[e];
    int p = base[d] + rk;
    const float4* eap = (const float4*)(ea + (size_t)e*16);
    float cs[16];
    float ae1[4] = {0,0,0,0}, ae2[4] = {0,0,0,0};
#pragma unroll
    for (int q = 0; q < 4; ++q){
        float4 v4 = eap[q];
        float vv[4] = {v4.x, v4.y, v4.z, v4.w};
#pragma unroll
        for (int r = 0; r < 4; ++r){
            int k = q*4 + r;
            float xv = vv[r];
            cs[k] = xv;
#pragma unroll
            for (int hh = 0; hh < 4; ++hh){
                ae1[hh] = fmaf(xv, w1[k*4+hh], ae1[hh]);
                ae2[hh] = fmaf(xv, w2[k*4+hh], ae2[hh]);
            }
        }
    }
    unsigned q8[4];
#pragma unroll
    for (int hh = 0; hh < 4; ++hh){
        int qv = (int)rintf(ae2[hh]*256.f) + 128;
        qv = qv < 0 ? 0 : (qv > 255 ? 255 : qv);
        q8[hh] = (unsigned)qv;
    }
    uint4 r;
    r.x = (unsigned)s;
    r.y = h16(ae1[0]) | (h16(ae1[1]) << 16);
    r.z = h16(ae1[2]) | (h16(ae1[3]) << 16);
    r.w = q8[0] | (q8[1] << 8) | (q8[2] << 16) | (q8[3] << 24);
    rec[p] = r;
    // block-reduce column sums -> partials[block][16]
#pragma unroll
    for (int k = 0; k < 16; ++k){
        float v = cs[k];
        v += __shfl_xor(v,1); v += __shfl_xor(v,2); v += __shfl_xor(v,4);
        v += __shfl_xor(v,8); v += __shfl_xor(v,16); v += __shfl_xor(v,32);
        if ((threadIdx.x & 63) == 0) red[k*4 + (threadIdx.x>>6)] = v;
    }
    __syncthreads();
    if (threadIdx.x < 16){
        float v = red[threadIdx.x*4] + red[threadIdx.x*4+1] + red[threadIdx.x*4+2] + red[threadIdx.x*4+3];
        partials[blockIdx.x*16 + threadIdx.x] = v;
    }
}

__global__ __launch_bounds__(256) void k_prep2(float* __restrict__ small, const float* __restrict__ partials){
    __shared__ float sm[256];
    __shared__ float mean_s[16];
    int t = threadIdx.x;
    float v = 0.f;
    for (int r = (t>>4); r < EDGE_BLOCKS; r += 16) v += partials[r*16 + (t&15)];
    sm[t] = v;
    __syncthreads();
    if (t < 16){
        float s = 0.f;
#pragma unroll
        for (int i = 0; i < 16; ++i) s += sm[t + 16*i];
        float m = s * (1.0f/(float)E_EDGES);
        mean_s[t] = m; small[16+t] = m;
    }
    __syncthreads();
    if (t < 4){
        float a1 = 0.f, a2 = 0.f;
#pragma unroll
        for (int k = 0; k < 16; ++k){
            a1 = fmaf(mean_s[k], small[32 + k*4 + t], a1);
            a2 = fmaf(mean_s[k], small[96 + k*4 + t], a2);
        }
        small[160+t] = a1; small[164+t] = a2;
    }
}

// One wave per node, lane = head*16+chan. Per edge: one uniform 16B record,
// w = exp(lrelu(a_s[si]+a_d[n]+ae)) computed inline, fp8 h gather (L2-resident).
template<int L>
__global__ __launch_bounds__(256) void k_agg(const uint4* __restrict__ recs, const int* __restrict__ base,
                                             const unsigned char* __restrict__ hb8,
                                             const unsigned short* __restrict__ a_s,
                                             const unsigned short* __restrict__ a_d,
                                             const float* __restrict__ aeloop, const float* __restrict__ bias,
                                             float* __restrict__ out){
    int lane = threadIdx.x & 63;
    int n = blockIdx.x*4 + (threadIdx.x >> 6);
    int hh = lane >> 4;
    float ad_v = bf2f(a_d[n*4+hh]);
    float wL = __expf(lrelu(bf2f(a_s[n*4+hh]) + ad_v + aeloop[hh]));
    float s0 = wL, s1 = 0.f, s2 = 0.f, s3 = 0.f;
    float acc0 = wL * dec8(hb8[(size_t)n*64 + lane]);
    float acc1 = 0.f, acc2 = 0.f, acc3 = 0.f;
    int b0 = base[n], b1 = base[n+1];

    auto aesel = [&](const uint4& r) -> float {
        if constexpr (L == 1){
            return f16dec(((hh < 2) ? r.y : r.z) >> ((hh & 1)*16));
        } else {
            return (float)((int)((r.w >> (hh*8)) & 255u) - 128) * 0.00390625f;
        }
    };

    int p = b0;
    for (; p + 4 <= b1; p += 4){
        uint4 rA = recs[p], rB = recs[p+1], rC = recs[p+2], rD = recs[p+3];
        float hvA = dec8(hb8[(size_t)rA.x*64 + lane]);
        float hvB = dec8(hb8[(size_t)rB.x*64 + lane]);
        float hvC = dec8(hb8[(size_t)rC.x*64 + lane]);
        float hvD = dec8(hb8[(size_t)rD.x*64 + lane]);
        float wA = __expf(lrelu(bf2f(a_s[rA.x*4+hh]) + ad_v + aesel(rA)));
        float wB = __expf(lrelu(bf2f(a_s[rB.x*4+hh]) + ad_v + aesel(rB)));
        float wC = __expf(lrelu(bf2f(a_s[rC.x*4+hh]) + ad_v + aesel(rC)));
        float wD = __expf(lrelu(bf2f(a_s[rD.x*4+hh]) + ad_v + aesel(rD)));
        s0 += wA; acc0 = fmaf(wA, hvA, acc0);
        s1 += wB; acc1 = fmaf(wB, hvB, acc1);
        s2 += wC; acc2 = fmaf(wC, hvC, acc2);
        s3 += wD; acc3 = fmaf(wD, hvD, acc3);
    }
    for (; p < b1; ++p){
        uint4 r = recs[p];
        float hv = dec8(hb8[(size_t)r.x*64 + lane]);
        float w = __expf(lrelu(bf2f(a_s[r.x*4+hh]) + ad_v + aesel(r)));
        s1 += w; acc1 = fmaf(w, hv, acc1);
    }
    float s = (s0 + s1) + (s2 + s3);
    float val = ((acc0 + acc1) + (acc2 + acc3)) / (s + 1e-16f) + bias[lane];
    out[(size_t)n*64 + lane] = fmaxf(val, 0.f);
}

__global__ __launch_bounds__(256) void k_head(const float* __restrict__ h2,
                                              const float* __restrict__ lw1, const float* __restrict__ lb1,
                                              const float* __restrict__ lw2, const float* __restrict__ lb2,
                                              float* __restrict__ out){
    int n = blockIdx.x*256 + threadIdx.x;
    if (n >= N_NODES) return;
    float y16[16];
#pragma unroll
    for (int j = 0; j < 16; ++j) y16[j] = lb1[j];
    const float4* hp = (const float4*)(h2 + (size_t)n*64);
#pragma unroll
    for (int k4 = 0; k4 < 16; ++k4){
        float4 hv = hp[k4];
        float hvv[4] = {hv.x, hv.y, hv.z, hv.w};
#pragma unroll
        for (int r = 0; r < 4; ++r){
            float x = hvv[r];
            int k = k4*4 + r;
#pragma unroll
            for (int j = 0; j < 16; ++j) y16[j] = fmaf(x, lw1[k*16+j], y16[j]);
        }
    }
    float y[40];
#pragma unroll
    for (int o = 0; o < 40; ++o) y[o] = lb2[o];
#pragma unroll
    for (int j = 0; j < 16; ++j){
        float x = y16[j];
#pragma unroll
        for (int o = 0; o < 40; ++o) y[o] = fmaf(x, lw2[j*40+o], y[o]);
    }
    float mx = y[0];
#pragma unroll
    for (int o = 1; o < 40; ++o) mx = fmaxf(mx, y[o]);
    float sum = 0.f;
#pragma unroll
    for (int o = 0; o < 40; ++o) sum += __expf(y[o] - mx);
    float ls = __logf(sum) + mx;
    float* op = out + (size_t)n*40;
#pragma unroll
    for (int o = 0; o < 40; ++o) op[o] = y[o] - ls;
}

extern "C" void kernel_launch(void* const* d_in, const int* in_sizes, int n_in,
                              void* d_out, int out_size, void* d_ws, size_t ws_size,
                              hipStream_t stream){
    const float* x     = (const float*)d_in[0];
    const int*   ei    = (const int*)  d_in[1];
    const float* ea    = (const float*)d_in[2];
    const float* W1    = (const float*)d_in[3];
    const float* atts1 = (const float*)d_in[4];
    const float* attd1 = (const float*)d_in[5];
    const float* We1   = (const float*)d_in[6];
    const float* atte1 = (const float*)d_in[7];
    const float* b1    = (const float*)d_in[8];
    const float* W2    = (const float*)d_in[9];
    const float* atts2 = (const float*)d_in[10];
    const float* attd2 = (const float*)d_in[11];
    const float* We2   = (const float*)d_in[12];
    const float* atte2 = (const float*)d_in[13];
    const float* b2    = (const float*)d_in[14];
    const float* lw1   = (const float*)d_in[15];
    const float* lb1   = (const float*)d_in[16];
    const float* lw2   = (const float*)d_in[17];
    const float* lb2   = (const float*)d_in[18];
    float* outp = (float*)d_out;

    const int* srcp = ei;
    const int* dstp = ei + E_EDGES;

    char* ws = (char*)d_ws;
    size_t off = 0;
    auto alloc = [&](size_t bytes) -> void* {
        void* p = ws + off;
        off = (off + bytes + 255) & ~(size_t)255;
        return p;
    };
    float*  smallf   = (float*) alloc(256*sizeof(float));
    float*  partials = (float*) alloc((size_t)EDGE_BLOCKS*16*sizeof(float));
    int*    deg      = (int*)   alloc((size_t)N_NODES*sizeof(int));
    int*    base     = (int*)   alloc((size_t)(N_NODES+1)*sizeof(int));
    int*    bsum     = (int*)   alloc((size_t)(SCAN_BLOCKS+1)*sizeof(int));
    int*    boff     = (int*)   alloc((size_t)(SCAN_BLOCKS+1)*sizeof(int));
    unsigned short* rank = (unsigned short*)alloc((size_t)E_EDGES*sizeof(unsigned short));
    uint4*  rec      = (uint4*) alloc((size_t)E_EDGES*16);
    unsigned char* hb8 = (unsigned char*)alloc((size_t)N_NODES*64);
    float*  obuf     = (float*) alloc((size_t)N_NODES*64*sizeof(float));
    unsigned short* asb = (unsigned short*)alloc((size_t)N_NODES*4*sizeof(unsigned short));
    unsigned short* adb = (unsigned short*)alloc((size_t)N_NODES*4*sizeof(unsigned short));

    const int NB = N_NODES/4;             // 12500
    const int HB = (N_NODES + 255)/256;   // 196

    hipMemsetAsync(deg, 0, (size_t)N_NODES*sizeof(int), stream);
    k_prep1<<<1, 64, 0, stream>>>(We1, atte1, We2, atte2, smallf);
    k_hist<<<(E_EDGES/4 + 255)/256, 256, 0, stream>>>((const int4*)dstp, deg, (ushort4*)rank);
    k_scan_a<<<SCAN_BLOCKS, 256, 0, stream>>>(deg, bsum);
    k_scan_b<<<1, 256, 0, stream>>>(bsum, boff);
    k_scan_c<<<SCAN_BLOCKS, 256, 0, stream>>>(deg, boff, base);

    // ---- layer 1 ----
    k_node<128><<<NB, 256, 0, stream>>>(x, W1, atts1, attd1, hb8, asb, adb);
    k_edges<<<EDGE_BLOCKS, 256, 0, stream>>>(srcp, dstp, rank, ea, smallf, base, rec, partials);
    k_prep2<<<1, 256, 0, stream>>>(smallf, partials);
    k_agg<1><<<NB, 256, 0, stream>>>(rec, base, hb8, asb, adb, smallf + 160, b1, obuf);

    // ---- layer 2 ----
    k_node<64><<<NB, 256, 0, stream>>>(obuf, W2, atts2, attd2, hb8, asb, adb);
    k_agg<2><<<NB, 256, 0, stream>>>(rec, base, hb8, asb, adb, smallf + 164, b2, obuf);

    // ---- head ----
    k_head<<<HB, 256, 0, stream>>>(obuf, lw1, lb1, lw2, lb2, outp);
}

// Round 8
// 377.745 us; speedup vs baseline: 1.3454x; 1.2265x over previous
//
#include <hip/hip_runtime.h>
#include <hip/hip_fp16.h>

#define N_NODES 50000
#define E_EDGES 1600000
#define NEG 0.2f
#define EDGE_BLOCKS 6250                    // one edge per thread: 6250*256 == E_EDGES
#define RED_BLOCKS 64
#define SCAN_BLOCKS ((N_NODES + 255)/256)   // 196

__device__ __forceinline__ float lrelu(float x){ return fmaxf(x, NEG*x); }
__device__ __forceinline__ float bcastlane(float v, int k){
    return __int_as_float(__builtin_amdgcn_readlane(__float_as_int(v), k));
}
__device__ __forceinline__ unsigned bf16rn(float x){
    unsigned u = __float_as_uint(x);
    return (u + 0x7FFFu + ((u >> 16) & 1u)) >> 16;
}
__device__ __forceinline__ float bf2f(unsigned short u){
    return __uint_as_float(((unsigned)u) << 16);
}
__device__ __forceinline__ unsigned h16(float x){
    return (unsigned)__half_as_ushort(__float2half(x));
}
__device__ __forceinline__ float f16dec(unsigned u){
    return __half2float(__ushort_as_half((unsigned short)(u & 0xFFFFu)));
}

// ---- fp8 e4m3 (OCP) encode/decode: hw builtins when available, manual fallback ----
#if __has_builtin(__builtin_amdgcn_cvt_f32_fp8) && __has_builtin(__builtin_amdgcn_cvt_pk_fp8_f32)
__device__ __forceinline__ unsigned enc8(float x){
    return (unsigned)__builtin_amdgcn_cvt_pk_fp8_f32(x, x, 0, false) & 0xFFu;
}
__device__ __forceinline__ float dec8(unsigned b){
    return __builtin_amdgcn_cvt_f32_fp8((int)b, 0);
}
#else
__device__ __forceinline__ unsigned enc8(float x){
    float ax = fabsf(x); unsigned s = (x < 0.f) ? 0x80u : 0u;
    if (ax < 0.015625f){
        int q = (int)rintf(ax * 512.f);          // subnormal quantum 2^-9
        return s | (unsigned)q;
    }
    if (ax >= 448.f) return s | 0x7Eu;           // max finite e4m3fn
    int ee; float mm = frexpf(ax, &ee);          // ax = mm*2^ee, mm in [0.5,1)
    int q = (int)rintf(mm * 16.f);               // [8,16]
    int E = ee + 6;
    if (q == 16){ q = 8; ++E; }
    if (E > 15){ return s | 0x7Eu; }
    return s | ((unsigned)E << 3) | (unsigned)(q - 8);
}
__device__ __forceinline__ float dec8(unsigned b){
    unsigned s = b >> 7, e = (b >> 3) & 15u, m = b & 7u;
    float mag = e ? __uint_as_float(((e + 120u) << 23) | (m << 20))
                  : (float)m * 0.001953125f;
    return s ? -mag : mag;
}
#endif

// small[] layout (floats): [16..32) mean, [32..96) WeAtt1[k*4+h], [96..160) WeAtt2,
// [160..164) aeloop1, [164..168) aeloop2

__global__ void k_prep1(const float* __restrict__ We1, const float* __restrict__ atte1,
                        const float* __restrict__ We2, const float* __restrict__ atte2,
                        float* __restrict__ small){
    int t = threadIdx.x;            // 64 threads: t = k*4+h
    int k = t >> 2, hh = t & 3;
    float w1 = 0.f, w2 = 0.f;
    for (int c = 0; c < 16; ++c){
        w1 = fmaf(We1[k*64 + hh*16 + c], atte1[hh*16 + c], w1);
        w2 = fmaf(We2[k*64 + hh*16 + c], atte2[hh*16 + c], w2);
    }
    small[32 + t] = w1;
    small[96 + t] = w2;
}

// histogram + per-edge rank within its dst (atomicAdd return value), rank as u16
__global__ __launch_bounds__(256) void k_hist(const int4* __restrict__ dst4, int* __restrict__ deg,
                                              ushort4* __restrict__ rank4){
    int i = blockIdx.x*256 + threadIdx.x;
    if (i < E_EDGES/4){
        int4 v = dst4[i];
        ushort4 r;
        r.x = (unsigned short)atomicAdd(&deg[v.x], 1);
        r.y = (unsigned short)atomicAdd(&deg[v.y], 1);
        r.z = (unsigned short)atomicAdd(&deg[v.z], 1);
        r.w = (unsigned short)atomicAdd(&deg[v.w], 1);
        rank4[i] = r;
    }
}

// ---- hierarchical scan ----
__global__ __launch_bounds__(256) void k_scan_a(const int* __restrict__ deg, int* __restrict__ bsum){
    int i = blockIdx.x*256 + threadIdx.x;
    int v = (i < N_NODES) ? deg[i] : 0;
    v += __shfl_xor(v,1); v += __shfl_xor(v,2); v += __shfl_xor(v,4);
    v += __shfl_xor(v,8); v += __shfl_xor(v,16); v += __shfl_xor(v,32);
    __shared__ int ws[4];
    if ((threadIdx.x & 63) == 0) ws[threadIdx.x >> 6] = v;
    __syncthreads();
    if (threadIdx.x == 0) bsum[blockIdx.x] = ws[0] + ws[1] + ws[2] + ws[3];
}

__global__ __launch_bounds__(256) void k_scan_b(const int* __restrict__ bsum, int* __restrict__ boff){
    __shared__ int sm[256];
    int t = threadIdx.x;
    int v = (t < SCAN_BLOCKS) ? bsum[t] : 0;
    sm[t] = v;
    __syncthreads();
    for (int off = 1; off < 256; off <<= 1){
        int u = (t >= off) ? sm[t-off] : 0;
        __syncthreads();
        sm[t] += u;
        __syncthreads();
    }
    boff[t] = (t > 0) ? sm[t-1] : 0;
    if (t == 0) boff[SCAN_BLOCKS] = sm[255];
}

__global__ __launch_bounds__(256) void k_scan_c(const int* __restrict__ deg, const int* __restrict__ boff,
                                                int* __restrict__ base){
    int i = blockIdx.x*256 + threadIdx.x;
    int lane = threadIdx.x & 63, wid = threadIdx.x >> 6;
    int v = (i < N_NODES) ? deg[i] : 0;
    int inc = v;
    for (int off = 1; off < 64; off <<= 1){
        int u = __shfl_up(inc, off);
        if (lane >= off) inc += u;
    }
    __shared__ int wsum[4];
    if (lane == 63) wsum[wid] = inc;
    __syncthreads();
    int wpre = 0;
#pragma unroll
    for (int w = 0; w < 4; ++w) wpre += (w < wid) ? wsum[w] : 0;
    int ex = boff[blockIdx.x] + wpre + inc - v;
    if (i < N_NODES) base[i] = ex;
    if (i == N_NODES - 1) base[N_NODES] = ex + v;
}

// h = in @ W -> fp8 gather table (3.2MB, fits per-XCD L2); a_s/a_d bf16 tables.
template<int FIN>
__global__ __launch_bounds__(256) void k_node(const float* __restrict__ in, const float* __restrict__ W,
                                              const float* __restrict__ att_s, const float* __restrict__ att_d,
                                              unsigned char* __restrict__ hb8,
                                              unsigned short* __restrict__ a_s,
                                              unsigned short* __restrict__ a_d){
    __shared__ float Wl[FIN*64];
    for (int i = threadIdx.x; i < FIN*64; i += 256) Wl[i] = W[i];
    __syncthreads();
    int lane = threadIdx.x & 63;
    int node = blockIdx.x*4 + (threadIdx.x >> 6);
    const float* row = in + (size_t)node*FIN;
    float x0 = row[lane];
    float x1 = 0.f;
    if constexpr (FIN == 128) x1 = row[64 + lane];
    float acc = 0.f;
#pragma unroll
    for (int k = 0; k < 64; ++k)
        acc = fmaf(bcastlane(x0, k), Wl[k*64 + lane], acc);
    if constexpr (FIN == 128){
#pragma unroll
        for (int k = 0; k < 64; ++k)
            acc = fmaf(bcastlane(x1, k), Wl[(64+k)*64 + lane], acc);
    }
    hb8[(size_t)node*64 + lane] = (unsigned char)enc8(acc);
    float ps = acc * att_s[lane];
    float pd = acc * att_d[lane];
    ps += __shfl_xor(ps,1); ps += __shfl_xor(ps,2); ps += __shfl_xor(ps,4); ps += __shfl_xor(ps,8);
    pd += __shfl_xor(pd,1); pd += __shfl_xor(pd,2); pd += __shfl_xor(pd,4); pd += __shfl_xor(pd,8);
    if ((lane & 15) == 0){
        a_s[node*4 + (lane>>4)] = (unsigned short)bf16rn(ps);
        a_d[node*4 + (lane>>4)] = (unsigned short)bf16rn(pd);
    }
}

// Edge pass: ae1 (f16x4) + ae2 (u8 fixed, (q-128)/256) -> ONE 16B scattered record
// {si, ae1pk01, ae1pk23, ae2q8x4}. No gathers except base[d]. Also ea column sums.
__global__ __launch_bounds__(256) void k_edges(const int* __restrict__ src, const int* __restrict__ dst,
                                               const unsigned short* __restrict__ rank,
                                               const float* __restrict__ ea, const float* __restrict__ small,
                                               const int* __restrict__ base, uint4* __restrict__ rec,
                                               float* __restrict__ partials){
    __shared__ float w1[64], w2[64];
    __shared__ float red[64];
    if (threadIdx.x < 64){ w1[threadIdx.x] = small[32+threadIdx.x]; w2[threadIdx.x] = small[96+threadIdx.x]; }
    __syncthreads();
    int e = blockIdx.x*256 + threadIdx.x;   // grid covers E exactly
    int s = src[e], d = dst[e];
    int rk = (int)rank[e];
    int p = base[d] + rk;
    const float4* eap = (const float4*)(ea + (size_t)e*16);
    float cs[16];
    float ae1[4] = {0,0,0,0}, ae2[4] = {0,0,0,0};
#pragma unroll
    for (int q = 0; q < 4; ++q){
        float4 v4 = eap[q];
        float vv[4] = {v4.x, v4.y, v4.z, v4.w};
#pragma unroll
        for (int r = 0; r < 4; ++r){
            int k = q*4 + r;
            float xv = vv[r];
            cs[k] = xv;
#pragma unroll
            for (int hh = 0; hh < 4; ++hh){
                ae1[hh] = fmaf(xv, w1[k*4+hh], ae1[hh]);
                ae2[hh] = fmaf(xv, w2[k*4+hh], ae2[hh]);
            }
        }
    }
    unsigned q8[4];
#pragma unroll
    for (int hh = 0; hh < 4; ++hh){
        int qv = (int)rintf(ae2[hh]*256.f) + 128;
        qv = qv < 0 ? 0 : (qv > 255 ? 255 : qv);
        q8[hh] = (unsigned)qv;
    }
    uint4 r;
    r.x = (unsigned)s;
    r.y = h16(ae1[0]) | (h16(ae1[1]) << 16);
    r.z = h16(ae1[2]) | (h16(ae1[3]) << 16);
    r.w = q8[0] | (q8[1] << 8) | (q8[2] << 16) | (q8[3] << 24);
    rec[p] = r;
    // block-reduce column sums -> partials[block][16]
#pragma unroll
    for (int k = 0; k < 16; ++k){
        float v = cs[k];
        v += __shfl_xor(v,1); v += __shfl_xor(v,2); v += __shfl_xor(v,4);
        v += __shfl_xor(v,8); v += __shfl_xor(v,16); v += __shfl_xor(v,32);
        if ((threadIdx.x & 63) == 0) red[k*4 + (threadIdx.x>>6)] = v;
    }
    __syncthreads();
    if (threadIdx.x < 16){
        float v = red[threadIdx.x*4] + red[threadIdx.x*4+1] + red[threadIdx.x*4+2] + red[threadIdx.x*4+3];
        partials[blockIdx.x*16 + threadIdx.x] = v;
    }
}

// Hierarchical reduce of partials[EDGE_BLOCKS][16] -> red16[RED_BLOCKS][16].
// Grid-stride of 16384 keeps each thread's column (idx&15) invariant.
__global__ __launch_bounds__(256) void k_red(const float* __restrict__ partials, float* __restrict__ red16){
    const int TOT = EDGE_BLOCKS*16;
    int t = threadIdx.x;
    float v = 0.f;
    for (int idx = blockIdx.x*256 + t; idx < TOT; idx += RED_BLOCKS*256) v += partials[idx];
    v += __shfl_xor(v,16); v += __shfl_xor(v,32);   // same-column lanes
    __shared__ float sm[64];
    int lane = t & 63, wid = t >> 6;
    if (lane < 16) sm[wid*16 + lane] = v;
    __syncthreads();
    if (t < 16) red16[blockIdx.x*16 + t] = sm[t] + sm[16+t] + sm[32+t] + sm[48+t];
}

__global__ __launch_bounds__(256) void k_prep2(float* __restrict__ small, const float* __restrict__ red16){
    __shared__ float sm[256];
    __shared__ float mean_s[16];
    int t = threadIdx.x;
    float v = 0.f;
    for (int r = (t>>4); r < RED_BLOCKS; r += 16) v += red16[r*16 + (t&15)];
    sm[t] = v;
    __syncthreads();
    if (t < 16){
        float s = 0.f;
#pragma unroll
        for (int i = 0; i < 16; ++i) s += sm[t + 16*i];
        float m = s * (1.0f/(float)E_EDGES);
        mean_s[t] = m; small[16+t] = m;
    }
    __syncthreads();
    if (t < 4){
        float a1 = 0.f, a2 = 0.f;
#pragma unroll
        for (int k = 0; k < 16; ++k){
            a1 = fmaf(mean_s[k], small[32 + k*4 + t], a1);
            a2 = fmaf(mean_s[k], small[96 + k*4 + t], a2);
        }
        small[160+t] = a1; small[164+t] = a2;
    }
}

// One wave per node, lane = head*16+chan. Per edge: one uniform 16B record,
// w = exp(lrelu(a_s[si]+a_d[n]+ae)) computed inline, fp8 h gather (L2-resident).
template<int L>
__global__ __launch_bounds__(256) void k_agg(const uint4* __restrict__ recs, const int* __restrict__ base,
                                             const unsigned char* __restrict__ hb8,
                                             const unsigned short* __restrict__ a_s,
                                             const unsigned short* __restrict__ a_d,
                                             const float* __restrict__ aeloop, const float* __restrict__ bias,
                                             float* __restrict__ out){
    int lane = threadIdx.x & 63;
    int n = blockIdx.x*4 + (threadIdx.x >> 6);
    int hh = lane >> 4;
    float ad_v = bf2f(a_d[n*4+hh]);
    float wL = __expf(lrelu(bf2f(a_s[n*4+hh]) + ad_v + aeloop[hh]));
    float s0 = wL, s1 = 0.f, s2 = 0.f, s3 = 0.f;
    float acc0 = wL * dec8(hb8[(size_t)n*64 + lane]);
    float acc1 = 0.f, acc2 = 0.f, acc3 = 0.f;
    int b0 = base[n], b1 = base[n+1];

    auto aesel = [&](const uint4& r) -> float {
        if constexpr (L == 1){
            return f16dec(((hh < 2) ? r.y : r.z) >> ((hh & 1)*16));
        } else {
            return (float)((int)((r.w >> (hh*8)) & 255u) - 128) * 0.00390625f;
        }
    };

    int p = b0;
    for (; p + 4 <= b1; p += 4){
        uint4 rA = recs[p], rB = recs[p+1], rC = recs[p+2], rD = recs[p+3];
        float hvA = dec8(hb8[(size_t)rA.x*64 + lane]);
        float hvB = dec8(hb8[(size_t)rB.x*64 + lane]);
        float hvC = dec8(hb8[(size_t)rC.x*64 + lane]);
        float hvD = dec8(hb8[(size_t)rD.x*64 + lane]);
        float wA = __expf(lrelu(bf2f(a_s[rA.x*4+hh]) + ad_v + aesel(rA)));
        float wB = __expf(lrelu(bf2f(a_s[rB.x*4+hh]) + ad_v + aesel(rB)));
        float wC = __expf(lrelu(bf2f(a_s[rC.x*4+hh]) + ad_v + aesel(rC)));
        float wD = __expf(lrelu(bf2f(a_s[rD.x*4+hh]) + ad_v + aesel(rD)));
        s0 += wA; acc0 = fmaf(wA, hvA, acc0);
        s1 += wB; acc1 = fmaf(wB, hvB, acc1);
        s2 += wC; acc2 = fmaf(wC, hvC, acc2);
        s3 += wD; acc3 = fmaf(wD, hvD, acc3);
    }
    for (; p < b1; ++p){
        uint4 r = recs[p];
        float hv = dec8(hb8[(size_t)r.x*64 + lane]);
        float w = __expf(lrelu(bf2f(a_s[r.x*4+hh]) + ad_v + aesel(r)));
        s1 += w; acc1 = fmaf(w, hv, acc1);
    }
    float s = (s0 + s1) + (s2 + s3);
    float val = ((acc0 + acc1) + (acc2 + acc3)) / (s + 1e-16f) + bias[lane];
    out[(size_t)n*64 + lane] = fmaxf(val, 0.f);
}

__global__ __launch_bounds__(256) void k_head(const float* __restrict__ h2,
                                              const float* __restrict__ lw1, const float* __restrict__ lb1,
                                              const float* __restrict__ lw2, const float* __restrict__ lb2,
                                              float* __restrict__ out){
    int n = blockIdx.x*256 + threadIdx.x;
    if (n >= N_NODES) return;
    float y16[16];
#pragma unroll
    for (int j = 0; j < 16; ++j) y16[j] = lb1[j];
    const float4* hp = (const float4*)(h2 + (size_t)n*64);
#pragma unroll
    for (int k4 = 0; k4 < 16; ++k4){
        float4 hv = hp[k4];
        float hvv[4] = {hv.x, hv.y, hv.z, hv.w};
#pragma unroll
        for (int r = 0; r < 4; ++r){
            float x = hvv[r];
            int k = k4*4 + r;
#pragma unroll
            for (int j = 0; j < 16; ++j) y16[j] = fmaf(x, lw1[k*16+j], y16[j]);
        }
    }
    float y[40];
#pragma unroll
    for (int o = 0; o < 40; ++o) y[o] = lb2[o];
#pragma unroll
    for (int j = 0; j < 16; ++j){
        float x = y16[j];
#pragma unroll
        for (int o = 0; o < 40; ++o) y[o] = fmaf(x, lw2[j*40+o], y[o]);
    }
    float mx = y[0];
#pragma unroll
    for (int o = 1; o < 40; ++o) mx = fmaxf(mx, y[o]);
    float sum = 0.f;
#pragma unroll
    for (int o = 0; o < 40; ++o) sum += __expf(y[o] - mx);
    float ls = __logf(sum) + mx;
    float* op = out + (size_t)n*40;
#pragma unroll
    for (int o = 0; o < 40; ++o) op[o] = y[o] - ls;
}

extern "C" void kernel_launch(void* const* d_in, const int* in_sizes, int n_in,
                              void* d_out, int out_size, void* d_ws, size_t ws_size,
                              hipStream_t stream){
    const float* x     = (const float*)d_in[0];
    const int*   ei    = (const int*)  d_in[1];
    const float* ea    = (const float*)d_in[2];
    const float* W1    = (const float*)d_in[3];
    const float* atts1 = (const float*)d_in[4];
    const float* attd1 = (const float*)d_in[5];
    const float* We1   = (const float*)d_in[6];
    const float* atte1 = (const float*)d_in[7];
    const float* b1    = (const float*)d_in[8];
    const float* W2    = (const float*)d_in[9];
    const float* atts2 = (const float*)d_in[10];
    const float* attd2 = (const float*)d_in[11];
    const float* We2   = (const float*)d_in[12];
    const float* atte2 = (const float*)d_in[13];
    const float* b2    = (const float*)d_in[14];
    const float* lw1   = (const float*)d_in[15];
    const float* lb1   = (const float*)d_in[16];
    const float* lw2   = (const float*)d_in[17];
    const float* lb2   = (const float*)d_in[18];
    float* outp = (float*)d_out;

    const int* srcp = ei;
    const int* dstp = ei + E_EDGES;

    char* ws = (char*)d_ws;
    size_t off = 0;
    auto alloc = [&](size_t bytes) -> void* {
        void* p = ws + off;
        off = (off + bytes + 255) & ~(size_t)255;
        return p;
    };
    float*  smallf   = (float*) alloc(256*sizeof(float));
    float*  partials = (float*) alloc((size_t)EDGE_BLOCKS*16*sizeof(float));
    float*  red16    = (float*) alloc((size_t)RED_BLOCKS*16*sizeof(float));
    int*    deg      = (int*)   alloc((size_t)N_NODES*sizeof(int));
    int*    base     = (int*)   alloc((size_t)(N_NODES+1)*sizeof(int));
    int*    bsum     = (int*)   alloc((size_t)(SCAN_BLOCKS+1)*sizeof(int));
    int*    boff     = (int*)   alloc((size_t)(SCAN_BLOCKS+1)*sizeof(int));
    unsigned short* rank = (unsigned short*)alloc((size_t)E_EDGES*sizeof(unsigned short));
    uint4*  rec      = (uint4*) alloc((size_t)E_EDGES*16);
    unsigned char* hb8 = (unsigned char*)alloc((size_t)N_NODES*64);
    float*  obuf     = (float*) alloc((size_t)N_NODES*64*sizeof(float));
    unsigned short* asb = (unsigned short*)alloc((size_t)N_NODES*4*sizeof(unsigned short));
    unsigned short* adb = (unsigned short*)alloc((size_t)N_NODES*4*sizeof(unsigned short));

    const int NB = N_NODES/4;             // 12500
    const int HB = (N_NODES + 255)/256;   // 196

    hipMemsetAsync(deg, 0, (size_t)N_NODES*sizeof(int), stream);
    k_prep1<<<1, 64, 0, stream>>>(We1, atte1, We2, atte2, smallf);
    k_hist<<<(E_EDGES/4 + 255)/256, 256, 0, stream>>>((const int4*)dstp, deg, (ushort4*)rank);
    k_scan_a<<<SCAN_BLOCKS, 256, 0, stream>>>(deg, bsum);
    k_scan_b<<<1, 256, 0, stream>>>(bsum, boff);
    k_scan_c<<<SCAN_BLOCKS, 256, 0, stream>>>(deg, boff, base);

    // ---- layer 1 ----
    k_node<128><<<NB, 256, 0, stream>>>(x, W1, atts1, attd1, hb8, asb, adb);
    k_edges<<<EDGE_BLOCKS, 256, 0, stream>>>(srcp, dstp, rank, ea, smallf, base, rec, partials);
    k_red<<<RED_BLOCKS, 256, 0, stream>>>(partials, red16);
    k_prep2<<<1, 256, 0, stream>>>(smallf, red16);
    k_agg<1><<<NB, 256, 0, stream>>>(rec, base, hb8, asb, adb, smallf + 160, b1, obuf);

    // ---- layer 2 ----
    k_node<64><<<NB, 256, 0, stream>>>(obuf, W2, atts2, attd2, hb8, asb, adb);
    k_agg<2><<<NB, 256, 0, stream>>>(rec, base, hb8, asb, adb, smallf + 164, b2, obuf);

    // ---- head ----
    k_head<<<HB, 256, 0, stream>>>(obuf, lw1, lb1, lw2, lb2, outp);
}